// Round 17
// baseline (1055.749 us; speedup 1.0000x reference)
//
#include <hip/hip_runtime.h>
#include <hip/hip_bf16.h>
#include <stdint.h>
#include <math.h>

typedef __attribute__((ext_vector_type(4))) float f32x4;
typedef __attribute__((ext_vector_type(8))) __bf16 bf16x8;
typedef __attribute__((ext_vector_type(8))) uint16_t u16x8;
typedef __attribute__((ext_vector_type(4))) uint32_t u32x4;

__device__ __forceinline__ uint16_t f2bf(float f) {
  union { float f; uint32_t u; } v; v.f = f;
  uint32_t r = v.u + 0x7FFFu + ((v.u >> 16) & 1u);
  return (uint16_t)(r >> 16);
}
__device__ __forceinline__ float bf2f(uint16_t b) {
  union { uint32_t u; float f; } v; v.u = ((uint32_t)b) << 16;
  return v.f;
}
__device__ __forceinline__ void gload16(const void* g, void* l) {
  __builtin_amdgcn_global_load_lds(
      (const __attribute__((address_space(1))) uint32_t*)g,
      (__attribute__((address_space(3))) uint32_t*)l, 16, 0, 0);
}

// ---------------------------------------------------------------- converts
__global__ __launch_bounds__(256) void k_conv_x(const float* __restrict__ x,
                                                uint16_t* __restrict__ comb) {
  int i = blockIdx.x * 256 + threadIdx.x;
  int base = i * 8;
  int row = base >> 9;
  int col = base & 511;
  const float* src = x + base;
  f32x4 a = *(const f32x4*)src;
  f32x4 b = *(const f32x4*)(src + 4);
  u16x8 o;
  o[0] = f2bf(a[0]); o[1] = f2bf(a[1]); o[2] = f2bf(a[2]); o[3] = f2bf(a[3]);
  o[4] = f2bf(b[0]); o[5] = f2bf(b[1]); o[6] = f2bf(b[2]); o[7] = f2bf(b[3]);
  *(u16x8*)(comb + (size_t)row * 576 + col) = o;
}

// tiled transpose: W[K][N] f32 -> WT[N][K] bf16, both sides coalesced
__global__ __launch_bounds__(256) void k_convT(const float* __restrict__ W,
                                               uint16_t* __restrict__ WT,
                                               int K, int N) {
  __shared__ float tile[64][65];
  const int t = threadIdx.x;
  const int n0 = blockIdx.x * 64, k0 = blockIdx.y * 64;
  const int c = t & 63, r0 = t >> 6;
#pragma unroll
  for (int rr = 0; rr < 16; ++rr) {
    int r = r0 * 16 + rr;
    tile[r][c] = W[(size_t)(k0 + r) * N + n0 + c];
  }
  __syncthreads();
#pragma unroll
  for (int rr = 0; rr < 16; ++rr) {
    int r = r0 * 16 + rr;
    WT[(size_t)(n0 + r) * K + k0 + c] = f2bf(tile[c][r]);
  }
}

__global__ __launch_bounds__(256) void k_conv(const float* __restrict__ W,
                                              uint16_t* __restrict__ O, int n) {
  int i = blockIdx.x * 256 + threadIdx.x;
  if (i < n) O[i] = f2bf(W[i]);
}

// ---------------------------------------------------------------- encoder e1
// f32 OpenBLAS-replica accumulation (bit-exact, PASSING since R10): per
// element ONE f32 accumulator, k ascending, kc-panel join at 384, bias after.
// R17 retile: BM=64 x BN=64, 4m x 4n per thread -> live state 32 floats
// (acc+res), VGPR ~56 <= 64 -> 8 waves/SIMD LEGAL WITHOUT SPILL (R16's
// bounds(,6) forced VGPR=40 < the 64-float live set -> 660MB scratch).
// LDS 16.7KB -> 8 blocks/CU. Mapping change only; per-element chain identical.
template <int K, bool RELU>
__global__ __launch_bounds__(256, 8)
void k_enc(const float* __restrict__ A, const float* __restrict__ W,
           const float* __restrict__ bias, float* __restrict__ C, int N) {
  __shared__ __align__(16) float xs[32][64];   // [k][m]
  __shared__ __align__(16) float ws[32][68];   // [k][n], +4 pad
  const int t = threadIdx.x;
  const int m0 = blockIdx.y * 64, n0 = blockIdx.x * 64;
  const int mg = t >> 4, ng = t & 15;  // rows mg*4..+3, cols ng*4..+3

  float res[4][4], acc[4][4];
#pragma unroll
  for (int i = 0; i < 4; ++i)
#pragma unroll
    for (int j = 0; j < 4; ++j) { res[i][j] = 0.f; acc[i][j] = 0.f; }

  const int xr = t >> 2, xk = (t & 3) * 8;   // A: row xr, 8 k-floats
  const int wrr = t >> 3, wj = (t & 7) * 8;  // W: row wrr, 8 n-floats

  for (int c = 0; c < K / 32; ++c) {
    const int k0 = c * 32;
    if (k0 > 0 && (k0 % 384) == 0) {  // OpenBLAS kc-panel boundary (Q=384)
#pragma unroll
      for (int i = 0; i < 4; ++i)
#pragma unroll
        for (int j = 0; j < 4; ++j) { res[i][j] += acc[i][j]; acc[i][j] = 0.f; }
    }
    __syncthreads();
#pragma unroll
    for (int u = 0; u < 2; ++u) {
      f32x4 v = *(const f32x4*)(A + (size_t)(m0 + xr) * K + k0 + xk + u * 4);
      xs[xk + u * 4 + 0][xr] = v[0];
      xs[xk + u * 4 + 1][xr] = v[1];
      xs[xk + u * 4 + 2][xr] = v[2];
      xs[xk + u * 4 + 3][xr] = v[3];
    }
#pragma unroll
    for (int u = 0; u < 2; ++u)
      *(f32x4*)&ws[wrr][wj + u * 4] =
          *(const f32x4*)(W + (size_t)(k0 + wrr) * N + n0 + wj + u * 4);
    __syncthreads();
#pragma unroll
    for (int k = 0; k < 32; ++k) {
      f32x4 xv = *(const f32x4*)&xs[k][mg * 4];
      f32x4 wv = *(const f32x4*)&ws[k][ng * 4];
#pragma unroll
      for (int j = 0; j < 4; ++j) {
        acc[0][j] = fmaf(xv[0], wv[j], acc[0][j]);
        acc[1][j] = fmaf(xv[1], wv[j], acc[1][j]);
        acc[2][j] = fmaf(xv[2], wv[j], acc[2][j]);
        acc[3][j] = fmaf(xv[3], wv[j], acc[3][j]);
      }
    }
  }
#pragma unroll
  for (int i = 0; i < 4; ++i)
#pragma unroll
    for (int j = 0; j < 4; ++j) res[i][j] += acc[i][j];  // final panel join

#pragma unroll
  for (int i = 0; i < 4; ++i) {
    f32x4 o;
#pragma unroll
    for (int j = 0; j < 4; ++j) {
      float v = res[i][j] + bias[n0 + ng * 4 + j];
      if (RELU) v = fmaxf(v, 0.f);
      o[j] = v;
    }
    *(f32x4*)(C + (size_t)(m0 + mg * 4 + i) * N + n0 + ng * 4) = o;
  }
}

// ---------------------------------------------------------------- encoder e2
// M-split (BM=32, 1024 blocks), full-K chain per element (R16, passing).
__global__ __launch_bounds__(256, 8)
void k_enc2(const float* __restrict__ A, const float* __restrict__ W,
            const float* __restrict__ bias, float* __restrict__ C) {
  __shared__ __align__(16) float xs[32][36];  // [k][m], +4 pad
  __shared__ __align__(16) float ws[32][68];  // [k][n], +4 pad
  const int t = threadIdx.x;
  const int m0 = blockIdx.x * 32;
  const int mg = t >> 4, ng = t & 15;  // rows mg*2..+1, cols ng*4..+3

  float res[2][4] = {}, acc[2][4] = {};
  const int xr = t >> 3, xk4 = (t & 7) * 4;
  const int wrr = t >> 3, wj = (t & 7) * 8;

  for (int c = 0; c < 32; ++c) {  // K = 1024
    const int k0 = c * 32;
    if (k0 > 0 && (k0 % 384) == 0) {  // kc-panel joins (384, 768)
#pragma unroll
      for (int i = 0; i < 2; ++i)
#pragma unroll
        for (int j = 0; j < 4; ++j) { res[i][j] += acc[i][j]; acc[i][j] = 0.f; }
    }
    __syncthreads();
    {
      f32x4 v = *(const f32x4*)(A + (size_t)(m0 + xr) * 1024 + k0 + xk4);
      xs[xk4 + 0][xr] = v[0];
      xs[xk4 + 1][xr] = v[1];
      xs[xk4 + 2][xr] = v[2];
      xs[xk4 + 3][xr] = v[3];
    }
#pragma unroll
    for (int u = 0; u < 2; ++u)
      *(f32x4*)&ws[wrr][wj + u * 4] =
          *(const f32x4*)(W + (size_t)(k0 + wrr) * 64 + wj + u * 4);
    __syncthreads();
#pragma unroll
    for (int k = 0; k < 32; ++k) {
      float x0 = xs[k][mg * 2 + 0];
      float x1 = xs[k][mg * 2 + 1];
      f32x4 wv = *(const f32x4*)&ws[k][ng * 4];
#pragma unroll
      for (int j = 0; j < 4; ++j) {
        acc[0][j] = fmaf(x0, wv[j], acc[0][j]);
        acc[1][j] = fmaf(x1, wv[j], acc[1][j]);
      }
    }
  }
#pragma unroll
  for (int i = 0; i < 2; ++i)
#pragma unroll
    for (int j = 0; j < 4; ++j) res[i][j] += acc[i][j];  // final panel join

#pragma unroll
  for (int i = 0; i < 2; ++i) {
    f32x4 o;
#pragma unroll
    for (int j = 0; j < 4; ++j) o[j] = res[i][j] + bias[ng * 4 + j];
    *(f32x4*)(C + (size_t)(m0 + mg * 2 + i) * 64 + ng * 4) = o;
  }
}

// ---------------------------------------------------------------- Hopfield
// PASSING arithmetic (R10): f32 state, numpy pairwise-8 tree, tie -> -1.
// Bitmask state + runtime loops (R14, no spill).
#define KNIFE_TAU 1e-6f

__device__ __forceinline__ uint32_t retrieve_bits(uint32_t sm,
                                                  const float (*w)[64],
                                                  int l) {
  for (int it = 0; it < 10; ++it) {
    bool changed = false;
    for (int i = 0; i < 64; ++i) {
      float r = 0.f;
#pragma unroll
      for (int c = 0; c < 8; ++c) {
        float wv = w[i][8 * c + l];
        uint32_t flip = ((~sm >> c) & 1u) << 31;  // bit clear -> s=-1 -> -wv
        r += __uint_as_float(__float_as_uint(wv) ^ flip);
      }
      r += __shfl_xor(r, 1);
      r += __shfl_xor(r, 2);
      r += __shfl_xor(r, 4);
      uint32_t nb = r > 0.f ? 1u : 0u;  // np: where(act > 0, 1, -1)
      if ((i & 7) == l) {
        uint32_t g = i >> 3;
        uint32_t ob = (sm >> g) & 1u;
        changed |= (nb != ob);
        sm = (sm & ~(1u << g)) | (nb << g);
      }
    }
    if (!__any(changed)) break;
  }
  return sm;
}

__device__ __forceinline__ uint64_t gather_mask_bits(uint32_t sm, int g) {
  uint64_t m = 0;
#pragma unroll
  for (int c = 0; c < 8; ++c) {
    unsigned long long b = __ballot(((sm >> c) & 1u) != 0u);
    m |= (uint64_t)((b >> (g * 8)) & 0xFFull) << (8 * c);
  }
  return m;
}

__global__ __launch_bounds__(256) void k_hopfield(const float* __restrict__ enc,
                                                  const float* __restrict__ hw,
                                                  uint16_t* __restrict__ comb) {
  __shared__ __align__(16) float w[64][64];
  const int t = threadIdx.x;
#pragma unroll
  for (int i = 0; i < 4; ++i)
    ((f32x4*)&w[0][0])[t * 4 + i] = ((const f32x4*)hw)[t * 4 + i];
  __syncthreads();

  const int lane = t & 63, wv = t >> 6;
  const int g = lane >> 3, l = lane & 7;
  const int sid = (blockIdx.x * 4 + wv) * 8 + g;
  const float* er = enc + (size_t)sid * 64;

  uint32_t imask = 0;
  int kc = -1;
  bool kpos = false;
#pragma unroll
  for (int c = 0; c < 8; ++c) {
    float v = er[8 * c + l];
    if (v > 0.f) imask |= (1u << c);
    if (kc < 0 && fabsf(v) < KNIFE_TAU) { kc = c; kpos = v > 0.f; }
  }
  unsigned long long kb = __ballot(kc >= 0);
  uint32_t gbits = (uint32_t)((kb >> (g * 8)) & 0xFFull);
  bool hasknife = gbits != 0;
  int klane = g * 8 + (__ffs(gbits) - 1);
  bool is_kl = hasknife && (lane == klane);
  uint32_t kbit = (kc >= 0) ? (1u << (kc & 7)) : 0u;

  uint32_t ma_bits = is_kl ? (imask | kbit) : imask;
  uint64_t mA = gather_mask_bits(retrieve_bits(ma_bits, w, l), g);
  uint64_t m = mA;

  if (__any(hasknife)) {
    if (hasknife) {
      uint32_t mb_bits = is_kl ? (imask & ~kbit) : imask;
      uint64_t mB = gather_mask_bits(retrieve_bits(mb_bits, w, l), g);
      if (mA != mB) {
        int kp = __shfl(kpos ? 1 : 0, klane);
        m = kp ? mA : mB;
      }
    }
  }

  uint32_t byte = (uint32_t)((m >> (8 * l)) & 0xFFull);
  u32x4 o;
#pragma unroll
  for (int p = 0; p < 4; ++p) {
    uint32_t lo = ((byte >> (2 * p)) & 1u) ? 0x3F80u : 0u;
    uint32_t hi = ((byte >> (2 * p + 1)) & 1u) ? 0x3F800000u : 0u;
    o[p] = lo | hi;
  }
  *(u32x4*)(comb + (size_t)sid * 576 + 512 + l * 8) = o;
}

// ---------------------------------------------------------------- bf16 MFMA GEMM
// global_load_lds staging (R12) + bijective T1 XCD swizzle.
__global__ __launch_bounds__(256)
void k_gemm_bf16(const uint16_t* __restrict__ A, const uint16_t* __restrict__ BT,
                 const float* __restrict__ bias, uint16_t* __restrict__ C,
                 int M, int N, int K, int relu) {
  constexpr int BM = 128, BN = 128, BK = 32;
  __shared__ __align__(16) uint16_t As[BM][BK];
  __shared__ __align__(16) uint16_t Bs[BN][BK];
  const int t = threadIdx.x;
  const int lane = t & 63, wid = t >> 6;
  const int wr = wid >> 1, wc = wid & 1;

  int bxi = blockIdx.x, byi = blockIdx.y;
  if ((gridDim.x & 7) == 0) {
    int L = byi * gridDim.x + bxi;
    int cpx = (gridDim.x * gridDim.y) >> 3;
    int T = (L & 7) * cpx + (L >> 3);
    byi = T / gridDim.x;
    bxi = T % gridDim.x;
  }
  const int bm = byi * BM, bn = bxi * BN;

  f32x4 acc[4][4] = {};

  const int l15 = lane & 15, kb = (lane >> 4) * 8;
  const int i0 = t, i1 = t + 256;
  const int r0 = i0 >> 2, c0 = (i0 & 3) * 8;
  const int r1 = i1 >> 2, c1 = (i1 & 3) * 8;
  const uint16_t* A0 = A + (size_t)(bm + r0) * K + c0;
  const uint16_t* A1 = A + (size_t)(bm + r1) * K + c1;
  const uint16_t* B0 = BT + (size_t)(bn + r0) * K + c0;
  const uint16_t* B1 = BT + (size_t)(bn + r1) * K + c1;
  uint16_t* Al = &As[0][0];
  uint16_t* Bl = &Bs[0][0];

  for (int kt = 0; kt < K / BK; ++kt) {
    __syncthreads();
    const int ko = kt * BK;
    gload16(A0 + ko, Al + i0 * 8);
    gload16(A1 + ko, Al + i1 * 8);
    gload16(B0 + ko, Bl + i0 * 8);
    gload16(B1 + ko, Bl + i1 * 8);
    __syncthreads();
    bf16x8 af[4], bf[4];
#pragma unroll
    for (int m = 0; m < 4; ++m)
      af[m] = *(const bf16x8*)&As[wr * 64 + m * 16 + l15][kb];
#pragma unroll
    for (int n = 0; n < 4; ++n)
      bf[n] = *(const bf16x8*)&Bs[wc * 64 + n * 16 + l15][kb];
#pragma unroll
    for (int m = 0; m < 4; ++m)
#pragma unroll
      for (int n = 0; n < 4; ++n)
        acc[m][n] = __builtin_amdgcn_mfma_f32_16x16x32_bf16(af[m], bf[n],
                                                            acc[m][n], 0, 0, 0);
  }
#pragma unroll
  for (int m = 0; m < 4; ++m) {
    int row = bm + wr * 64 + m * 16 + (lane >> 4) * 4;
#pragma unroll
    for (int n = 0; n < 4; ++n) {
      int col = bn + wc * 64 + n * 16 + l15;
      float bsv = bias[col];
#pragma unroll
      for (int r = 0; r < 4; ++r) {
        float v = acc[m][n][r] + bsv;
        if (relu) v = fmaxf(v, 0.f);
        C[(size_t)(row + r) * N + col] = f2bf(v);
      }
    }
  }
}

// ---------------------------------------------------------------- n3 (N=2)
__global__ __launch_bounds__(256) void k_n3(const uint16_t* __restrict__ h2,
                                            const uint16_t* __restrict__ w3,
                                            const float* __restrict__ b3,
                                            float* __restrict__ out, int M) {
  const int lane = threadIdx.x & 63;
  const int wglob = (blockIdx.x * 256 + threadIdx.x) >> 6;
  const int nw = (gridDim.x * 256) >> 6;
  u16x8 wa = *(const u16x8*)(w3 + lane * 16);
  u16x8 wb = *(const u16x8*)(w3 + lane * 16 + 8);
  u16x8 wc = *(const u16x8*)(w3 + 1024 + lane * 16);
  u16x8 wd = *(const u16x8*)(w3 + 1024 + lane * 16 + 8);
  const float b0 = b3[0], b1 = b3[1];
  for (int row = wglob; row < M; row += nw) {
    const uint16_t* hr = h2 + (size_t)row * 1024;
    u16x8 h0 = *(const u16x8*)(hr + lane * 8);
    u16x8 h1 = *(const u16x8*)(hr + 512 + lane * 8);
    float a0 = 0.f, a1 = 0.f;
#pragma unroll
    for (int e = 0; e < 4; ++e) {
      float h = bf2f(h0[e]);
      a0 = fmaf(h, bf2f(wa[2 * e]), a0);
      a1 = fmaf(h, bf2f(wa[2 * e + 1]), a1);
    }
#pragma unroll
    for (int e = 4; e < 8; ++e) {
      float h = bf2f(h0[e]);
      a0 = fmaf(h, bf2f(wb[2 * e - 8]), a0);
      a1 = fmaf(h, bf2f(wb[2 * e - 7]), a1);
    }
#pragma unroll
    for (int e = 0; e < 4; ++e) {
      float h = bf2f(h1[e]);
      a0 = fmaf(h, bf2f(wc[2 * e]), a0);
      a1 = fmaf(h, bf2f(wc[2 * e + 1]), a1);
    }
#pragma unroll
    for (int e = 4; e < 8; ++e) {
      float h = bf2f(h1[e]);
      a0 = fmaf(h, bf2f(wd[2 * e - 8]), a0);
      a1 = fmaf(h, bf2f(wd[2 * e - 7]), a1);
    }
#pragma unroll
    for (int off = 32; off; off >>= 1) {
      a0 += __shfl_xor(a0, off, 64);
      a1 += __shfl_xor(a1, off, 64);
    }
    if (lane == 0) {
      out[(size_t)row * 2 + 0] = a0 + b0;
      out[(size_t)row * 2 + 1] = a1 + b1;
    }
  }
}

// ---------------------------------------------------------------- launch
extern "C" void kernel_launch(void* const* d_in, const int* in_sizes, int n_in,
                              void* d_out, int out_size, void* d_ws, size_t ws_size,
                              hipStream_t stream) {
  const float* x     = (const float*)d_in[0];
  const float* e_w1  = (const float*)d_in[1];
  const float* e_b1  = (const float*)d_in[2];
  const float* e_w2  = (const float*)d_in[3];
  const float* e_b2  = (const float*)d_in[4];
  const float* hop_w = (const float*)d_in[5];
  const float* n_w1  = (const float*)d_in[6];
  const float* n_b1  = (const float*)d_in[7];
  const float* n_w2  = (const float*)d_in[8];
  const float* n_b2  = (const float*)d_in[9];
  const float* n_w3  = (const float*)d_in[10];
  const float* n_b3  = (const float*)d_in[11];
  float* out = (float*)d_out;
  char* ws = (char*)d_ws;

  float*    h1e  = (float*)(ws + 0);              // 32768x1024 f32, [0,128MB)
  uint16_t* h1   = (uint16_t*)(ws + 0);           // 32768x1024 bf16 (phase C)
  uint16_t* h2   = (uint16_t*)(ws + 67108864);    // bf16, written AFTER h1e dead
  uint16_t* comb = (uint16_t*)(ws + 134217728);
  float*    enc  = (float*)(ws + 171966464);
  uint16_t* w1t  = (uint16_t*)(ws + 180355072);
  uint16_t* w2t  = (uint16_t*)(ws + 181534720);
  uint16_t* w3b  = (uint16_t*)(ws + 183631872);

  k_conv_x<<<8192, 256, 0, stream>>>(x, comb);
  k_convT<<<dim3(1024 / 64, 576 / 64), 256, 0, stream>>>(n_w1, w1t, 576, 1024);
  k_convT<<<dim3(1024 / 64, 1024 / 64), 256, 0, stream>>>(n_w2, w2t, 1024, 1024);
  k_conv<<<(2048 + 255) / 256, 256, 0, stream>>>(n_w3, w3b, 2048);

  // encoder e1 — f32 OpenBLAS replica, 64x64 tile, 8 waves/SIMD no-spill
  k_enc<512, true><<<dim3(1024 / 64, 32768 / 64), 256, 0, stream>>>(
      x, e_w1, e_b1, h1e, 1024);
  // encoder e2 — M-split (BM=32, 1024 blocks), full-K chain per element
  k_enc2<<<1024, 256, 0, stream>>>(h1e, e_w2, e_b2, enc);

  // hopfield — bitmask state, runtime loops
  k_hopfield<<<32768 / 32, 256, 0, stream>>>(enc, hop_w, comb);

  // Q-network (bf16 MFMA, gload_lds + XCD swizzle)
  k_gemm_bf16<<<dim3(1024 / 128, 32768 / 128), 256, 0, stream>>>(
      comb, w1t, n_b1, h1, 32768, 1024, 576, 1);
  k_gemm_bf16<<<dim3(1024 / 128, 32768 / 128), 256, 0, stream>>>(
      h1, w2t, n_b2, h2, 32768, 1024, 1024, 1);
  k_n3<<<512, 256, 0, stream>>>(h2, w3b, n_b3, out, 32768);
}

// Round 18
// 974.731 us; speedup vs baseline: 1.0831x; 1.0831x over previous
//
#include <hip/hip_runtime.h>
#include <hip/hip_bf16.h>
#include <stdint.h>
#include <math.h>

typedef __attribute__((ext_vector_type(4))) float f32x4;
typedef __attribute__((ext_vector_type(8))) __bf16 bf16x8;
typedef __attribute__((ext_vector_type(8))) uint16_t u16x8;
typedef __attribute__((ext_vector_type(4))) uint32_t u32x4;

__device__ __forceinline__ uint16_t f2bf(float f) {
  union { float f; uint32_t u; } v; v.f = f;
  uint32_t r = v.u + 0x7FFFu + ((v.u >> 16) & 1u);
  return (uint16_t)(r >> 16);
}
__device__ __forceinline__ float bf2f(uint16_t b) {
  union { uint32_t u; float f; } v; v.u = ((uint32_t)b) << 16;
  return v.f;
}
__device__ __forceinline__ void gload16(const void* g, void* l) {
  __builtin_amdgcn_global_load_lds(
      (const __attribute__((address_space(1))) uint32_t*)g,
      (__attribute__((address_space(3))) uint32_t*)l, 16, 0, 0);
}

// ---------------------------------------------------------------- converts
__global__ __launch_bounds__(256) void k_conv_x(const float* __restrict__ x,
                                                uint16_t* __restrict__ comb) {
  int i = blockIdx.x * 256 + threadIdx.x;
  int base = i * 8;
  int row = base >> 9;
  int col = base & 511;
  const float* src = x + base;
  f32x4 a = *(const f32x4*)src;
  f32x4 b = *(const f32x4*)(src + 4);
  u16x8 o;
  o[0] = f2bf(a[0]); o[1] = f2bf(a[1]); o[2] = f2bf(a[2]); o[3] = f2bf(a[3]);
  o[4] = f2bf(b[0]); o[5] = f2bf(b[1]); o[6] = f2bf(b[2]); o[7] = f2bf(b[3]);
  *(u16x8*)(comb + (size_t)row * 576 + col) = o;
}

// tiled transpose: W[K][N] f32 -> WT[N][K] bf16, both sides coalesced
__global__ __launch_bounds__(256) void k_convT(const float* __restrict__ W,
                                               uint16_t* __restrict__ WT,
                                               int K, int N) {
  __shared__ float tile[64][65];
  const int t = threadIdx.x;
  const int n0 = blockIdx.x * 64, k0 = blockIdx.y * 64;
  const int c = t & 63, r0 = t >> 6;
#pragma unroll
  for (int rr = 0; rr < 16; ++rr) {
    int r = r0 * 16 + rr;
    tile[r][c] = W[(size_t)(k0 + r) * N + n0 + c];
  }
  __syncthreads();
#pragma unroll
  for (int rr = 0; rr < 16; ++rr) {
    int r = r0 * 16 + rr;
    WT[(size_t)(n0 + r) * K + k0 + c] = f2bf(tile[c][r]);
  }
}

__global__ __launch_bounds__(256) void k_conv(const float* __restrict__ W,
                                              uint16_t* __restrict__ O, int n) {
  int i = blockIdx.x * 256 + threadIdx.x;
  if (i < n) O[i] = f2bf(W[i]);
}

// ---------------------------------------------------------------- encoder e1
// f32 OpenBLAS-replica accumulation (bit-exact, PASSING since R10).
// R18: EXACT R14 configuration — the measured optimum (420us, VGPR=64,
// zero spill). R15/R16's (256,6) forced VGPR=40 -> 660MB scratch; R17's
// 64x64 retile + (256,8) gave VGPR=32 -> 240MB scratch. The 64-float live
// set pins VGPR=64 => 4 waves/SIMD is the max spill-free occupancy.
template <int K, bool RELU>
__global__ __launch_bounds__(256, 4)
void k_enc(const float* __restrict__ A, const float* __restrict__ W,
           const float* __restrict__ bias, float* __restrict__ C, int N) {
  __shared__ __align__(16) float xs[32][128];  // [k][m]
  __shared__ __align__(16) float ws[32][68];   // [k][n], +4 pad
  const int t = threadIdx.x;
  const int m0 = blockIdx.y * 128, n0 = blockIdx.x * 64;
  const int mg = t >> 4, ng = t & 15;

  float res[8][4], acc[8][4];
#pragma unroll
  for (int i = 0; i < 8; ++i)
#pragma unroll
    for (int j = 0; j < 4; ++j) { res[i][j] = 0.f; acc[i][j] = 0.f; }

  const int xr = t >> 1, xk = (t & 1) * 16;
  const int wrr = t >> 3, wj = (t & 7) * 8;

  for (int c = 0; c < K / 32; ++c) {
    const int k0 = c * 32;
    if (k0 > 0 && (k0 % 384) == 0) {  // OpenBLAS kc-panel boundary (Q=384)
#pragma unroll
      for (int i = 0; i < 8; ++i)
#pragma unroll
        for (int j = 0; j < 4; ++j) { res[i][j] += acc[i][j]; acc[i][j] = 0.f; }
    }
    __syncthreads();
#pragma unroll
    for (int u = 0; u < 4; ++u) {
      f32x4 v = *(const f32x4*)(A + (size_t)(m0 + xr) * K + k0 + xk + u * 4);
      xs[xk + u * 4 + 0][xr] = v[0];
      xs[xk + u * 4 + 1][xr] = v[1];
      xs[xk + u * 4 + 2][xr] = v[2];
      xs[xk + u * 4 + 3][xr] = v[3];
    }
#pragma unroll
    for (int u = 0; u < 2; ++u)
      *(f32x4*)&ws[wrr][wj + u * 4] =
          *(const f32x4*)(W + (size_t)(k0 + wrr) * N + n0 + wj + u * 4);
    __syncthreads();
#pragma unroll
    for (int k = 0; k < 32; ++k) {
      f32x4 x0 = *(const f32x4*)&xs[k][mg * 8];
      f32x4 x1 = *(const f32x4*)&xs[k][mg * 8 + 4];
      f32x4 wv = *(const f32x4*)&ws[k][ng * 4];
#pragma unroll
      for (int j = 0; j < 4; ++j) {
        acc[0][j] = fmaf(x0[0], wv[j], acc[0][j]);
        acc[1][j] = fmaf(x0[1], wv[j], acc[1][j]);
        acc[2][j] = fmaf(x0[2], wv[j], acc[2][j]);
        acc[3][j] = fmaf(x0[3], wv[j], acc[3][j]);
        acc[4][j] = fmaf(x1[0], wv[j], acc[4][j]);
        acc[5][j] = fmaf(x1[1], wv[j], acc[5][j]);
        acc[6][j] = fmaf(x1[2], wv[j], acc[6][j]);
        acc[7][j] = fmaf(x1[3], wv[j], acc[7][j]);
      }
    }
  }
#pragma unroll
  for (int i = 0; i < 8; ++i)
#pragma unroll
    for (int j = 0; j < 4; ++j) res[i][j] += acc[i][j];  // final panel join

#pragma unroll
  for (int i = 0; i < 8; ++i) {
    f32x4 o;
#pragma unroll
    for (int j = 0; j < 4; ++j) {
      float v = res[i][j] + bias[n0 + ng * 4 + j];
      if (RELU) v = fmaxf(v, 0.f);
      o[j] = v;
    }
    *(f32x4*)(C + (size_t)(m0 + mg * 8 + i) * N + n0 + ng * 4) = o;
  }
}

// ---------------------------------------------------------------- encoder e2
// M-split (BM=32, 1024 blocks), full-K chain per element (R16, passing).
// Live set 16 floats -> no spill at (256,8).
__global__ __launch_bounds__(256, 8)
void k_enc2(const float* __restrict__ A, const float* __restrict__ W,
            const float* __restrict__ bias, float* __restrict__ C) {
  __shared__ __align__(16) float xs[32][36];  // [k][m], +4 pad
  __shared__ __align__(16) float ws[32][68];  // [k][n], +4 pad
  const int t = threadIdx.x;
  const int m0 = blockIdx.x * 32;
  const int mg = t >> 4, ng = t & 15;  // rows mg*2..+1, cols ng*4..+3

  float res[2][4] = {}, acc[2][4] = {};
  const int xr = t >> 3, xk4 = (t & 7) * 4;
  const int wrr = t >> 3, wj = (t & 7) * 8;

  for (int c = 0; c < 32; ++c) {  // K = 1024
    const int k0 = c * 32;
    if (k0 > 0 && (k0 % 384) == 0) {  // kc-panel joins (384, 768)
#pragma unroll
      for (int i = 0; i < 2; ++i)
#pragma unroll
        for (int j = 0; j < 4; ++j) { res[i][j] += acc[i][j]; acc[i][j] = 0.f; }
    }
    __syncthreads();
    {
      f32x4 v = *(const f32x4*)(A + (size_t)(m0 + xr) * 1024 + k0 + xk4);
      xs[xk4 + 0][xr] = v[0];
      xs[xk4 + 1][xr] = v[1];
      xs[xk4 + 2][xr] = v[2];
      xs[xk4 + 3][xr] = v[3];
    }
#pragma unroll
    for (int u = 0; u < 2; ++u)
      *(f32x4*)&ws[wrr][wj + u * 4] =
          *(const f32x4*)(W + (size_t)(k0 + wrr) * 64 + wj + u * 4);
    __syncthreads();
#pragma unroll
    for (int k = 0; k < 32; ++k) {
      float x0 = xs[k][mg * 2 + 0];
      float x1 = xs[k][mg * 2 + 1];
      f32x4 wv = *(const f32x4*)&ws[k][ng * 4];
#pragma unroll
      for (int j = 0; j < 4; ++j) {
        acc[0][j] = fmaf(x0, wv[j], acc[0][j]);
        acc[1][j] = fmaf(x1, wv[j], acc[1][j]);
      }
    }
  }
#pragma unroll
  for (int i = 0; i < 2; ++i)
#pragma unroll
    for (int j = 0; j < 4; ++j) res[i][j] += acc[i][j];  // final panel join

#pragma unroll
  for (int i = 0; i < 2; ++i) {
    f32x4 o;
#pragma unroll
    for (int j = 0; j < 4; ++j) o[j] = res[i][j] + bias[ng * 4 + j];
    *(f32x4*)(C + (size_t)(m0 + mg * 2 + i) * 64 + ng * 4) = o;
  }
}

// ---------------------------------------------------------------- Hopfield
// PASSING arithmetic (R10): f32 state, numpy pairwise-8 tree, tie -> -1.
// Bitmask state + runtime loops (R14, no spill).
#define KNIFE_TAU 1e-6f

__device__ __forceinline__ uint32_t retrieve_bits(uint32_t sm,
                                                  const float (*w)[64],
                                                  int l) {
  for (int it = 0; it < 10; ++it) {
    bool changed = false;
    for (int i = 0; i < 64; ++i) {
      float r = 0.f;
#pragma unroll
      for (int c = 0; c < 8; ++c) {
        float wv = w[i][8 * c + l];
        uint32_t flip = ((~sm >> c) & 1u) << 31;  // bit clear -> s=-1 -> -wv
        r += __uint_as_float(__float_as_uint(wv) ^ flip);
      }
      r += __shfl_xor(r, 1);
      r += __shfl_xor(r, 2);
      r += __shfl_xor(r, 4);
      uint32_t nb = r > 0.f ? 1u : 0u;  // np: where(act > 0, 1, -1)
      if ((i & 7) == l) {
        uint32_t g = i >> 3;
        uint32_t ob = (sm >> g) & 1u;
        changed |= (nb != ob);
        sm = (sm & ~(1u << g)) | (nb << g);
      }
    }
    if (!__any(changed)) break;
  }
  return sm;
}

__device__ __forceinline__ uint64_t gather_mask_bits(uint32_t sm, int g) {
  uint64_t m = 0;
#pragma unroll
  for (int c = 0; c < 8; ++c) {
    unsigned long long b = __ballot(((sm >> c) & 1u) != 0u);
    m |= (uint64_t)((b >> (g * 8)) & 0xFFull) << (8 * c);
  }
  return m;
}

__global__ __launch_bounds__(256) void k_hopfield(const float* __restrict__ enc,
                                                  const float* __restrict__ hw,
                                                  uint16_t* __restrict__ comb) {
  __shared__ __align__(16) float w[64][64];
  const int t = threadIdx.x;
#pragma unroll
  for (int i = 0; i < 4; ++i)
    ((f32x4*)&w[0][0])[t * 4 + i] = ((const f32x4*)hw)[t * 4 + i];
  __syncthreads();

  const int lane = t & 63, wv = t >> 6;
  const int g = lane >> 3, l = lane & 7;
  const int sid = (blockIdx.x * 4 + wv) * 8 + g;
  const float* er = enc + (size_t)sid * 64;

  uint32_t imask = 0;
  int kc = -1;
  bool kpos = false;
#pragma unroll
  for (int c = 0; c < 8; ++c) {
    float v = er[8 * c + l];
    if (v > 0.f) imask |= (1u << c);
    if (kc < 0 && fabsf(v) < KNIFE_TAU) { kc = c; kpos = v > 0.f; }
  }
  unsigned long long kb = __ballot(kc >= 0);
  uint32_t gbits = (uint32_t)((kb >> (g * 8)) & 0xFFull);
  bool hasknife = gbits != 0;
  int klane = g * 8 + (__ffs(gbits) - 1);
  bool is_kl = hasknife && (lane == klane);
  uint32_t kbit = (kc >= 0) ? (1u << (kc & 7)) : 0u;

  uint32_t ma_bits = is_kl ? (imask | kbit) : imask;
  uint64_t mA = gather_mask_bits(retrieve_bits(ma_bits, w, l), g);
  uint64_t m = mA;

  if (__any(hasknife)) {
    if (hasknife) {
      uint32_t mb_bits = is_kl ? (imask & ~kbit) : imask;
      uint64_t mB = gather_mask_bits(retrieve_bits(mb_bits, w, l), g);
      if (mA != mB) {
        int kp = __shfl(kpos ? 1 : 0, klane);
        m = kp ? mA : mB;
      }
    }
  }

  uint32_t byte = (uint32_t)((m >> (8 * l)) & 0xFFull);
  u32x4 o;
#pragma unroll
  for (int p = 0; p < 4; ++p) {
    uint32_t lo = ((byte >> (2 * p)) & 1u) ? 0x3F80u : 0u;
    uint32_t hi = ((byte >> (2 * p + 1)) & 1u) ? 0x3F800000u : 0u;
    o[p] = lo | hi;
  }
  *(u32x4*)(comb + (size_t)sid * 576 + 512 + l * 8) = o;
}

// ---------------------------------------------------------------- bf16 MFMA GEMM
// global_load_lds staging (R12) + bijective T1 XCD swizzle (R15).
__global__ __launch_bounds__(256)
void k_gemm_bf16(const uint16_t* __restrict__ A, const uint16_t* __restrict__ BT,
                 const float* __restrict__ bias, uint16_t* __restrict__ C,
                 int M, int N, int K, int relu) {
  constexpr int BM = 128, BN = 128, BK = 32;
  __shared__ __align__(16) uint16_t As[BM][BK];
  __shared__ __align__(16) uint16_t Bs[BN][BK];
  const int t = threadIdx.x;
  const int lane = t & 63, wid = t >> 6;
  const int wr = wid >> 1, wc = wid & 1;

  int bxi = blockIdx.x, byi = blockIdx.y;
  if ((gridDim.x & 7) == 0) {
    int L = byi * gridDim.x + bxi;
    int cpx = (gridDim.x * gridDim.y) >> 3;
    int T = (L & 7) * cpx + (L >> 3);
    byi = T / gridDim.x;
    bxi = T % gridDim.x;
  }
  const int bm = byi * BM, bn = bxi * BN;

  f32x4 acc[4][4] = {};

  const int l15 = lane & 15, kb = (lane >> 4) * 8;
  const int i0 = t, i1 = t + 256;
  const int r0 = i0 >> 2, c0 = (i0 & 3) * 8;
  const int r1 = i1 >> 2, c1 = (i1 & 3) * 8;
  const uint16_t* A0 = A + (size_t)(bm + r0) * K + c0;
  const uint16_t* A1 = A + (size_t)(bm + r1) * K + c1;
  const uint16_t* B0 = BT + (size_t)(bn + r0) * K + c0;
  const uint16_t* B1 = BT + (size_t)(bn + r1) * K + c1;
  uint16_t* Al = &As[0][0];
  uint16_t* Bl = &Bs[0][0];

  for (int kt = 0; kt < K / BK; ++kt) {
    __syncthreads();
    const int ko = kt * BK;
    gload16(A0 + ko, Al + i0 * 8);
    gload16(A1 + ko, Al + i1 * 8);
    gload16(B0 + ko, Bl + i0 * 8);
    gload16(B1 + ko, Bl + i1 * 8);
    __syncthreads();
    bf16x8 af[4], bf[4];
#pragma unroll
    for (int m = 0; m < 4; ++m)
      af[m] = *(const bf16x8*)&As[wr * 64 + m * 16 + l15][kb];
#pragma unroll
    for (int n = 0; n < 4; ++n)
      bf[n] = *(const bf16x8*)&Bs[wc * 64 + n * 16 + l15][kb];
#pragma unroll
    for (int m = 0; m < 4; ++m)
#pragma unroll
      for (int n = 0; n < 4; ++n)
        acc[m][n] = __builtin_amdgcn_mfma_f32_16x16x32_bf16(af[m], bf[n],
                                                            acc[m][n], 0, 0, 0);
  }
#pragma unroll
  for (int m = 0; m < 4; ++m) {
    int row = bm + wr * 64 + m * 16 + (lane >> 4) * 4;
#pragma unroll
    for (int n = 0; n < 4; ++n) {
      int col = bn + wc * 64 + n * 16 + l15;
      float bsv = bias[col];
#pragma unroll
      for (int r = 0; r < 4; ++r) {
        float v = acc[m][n][r] + bsv;
        if (relu) v = fmaxf(v, 0.f);
        C[(size_t)(row + r) * N + col] = f2bf(v);
      }
    }
  }
}

// ---------------------------------------------------------------- n3 (N=2)
__global__ __launch_bounds__(256) void k_n3(const uint16_t* __restrict__ h2,
                                            const uint16_t* __restrict__ w3,
                                            const float* __restrict__ b3,
                                            float* __restrict__ out, int M) {
  const int lane = threadIdx.x & 63;
  const int wglob = (blockIdx.x * 256 + threadIdx.x) >> 6;
  const int nw = (gridDim.x * 256) >> 6;
  u16x8 wa = *(const u16x8*)(w3 + lane * 16);
  u16x8 wb = *(const u16x8*)(w3 + lane * 16 + 8);
  u16x8 wc = *(const u16x8*)(w3 + 1024 + lane * 16);
  u16x8 wd = *(const u16x8*)(w3 + 1024 + lane * 16 + 8);
  const float b0 = b3[0], b1 = b3[1];
  for (int row = wglob; row < M; row += nw) {
    const uint16_t* hr = h2 + (size_t)row * 1024;
    u16x8 h0 = *(const u16x8*)(hr + lane * 8);
    u16x8 h1 = *(const u16x8*)(hr + 512 + lane * 8);
    float a0 = 0.f, a1 = 0.f;
#pragma unroll
    for (int e = 0; e < 4; ++e) {
      float h = bf2f(h0[e]);
      a0 = fmaf(h, bf2f(wa[2 * e]), a0);
      a1 = fmaf(h, bf2f(wa[2 * e + 1]), a1);
    }
#pragma unroll
    for (int e = 4; e < 8; ++e) {
      float h = bf2f(h0[e]);
      a0 = fmaf(h, bf2f(wb[2 * e - 8]), a0);
      a1 = fmaf(h, bf2f(wb[2 * e - 7]), a1);
    }
#pragma unroll
    for (int e = 0; e < 4; ++e) {
      float h = bf2f(h1[e]);
      a0 = fmaf(h, bf2f(wc[2 * e]), a0);
      a1 = fmaf(h, bf2f(wc[2 * e + 1]), a1);
    }
#pragma unroll
    for (int e = 4; e < 8; ++e) {
      float h = bf2f(h1[e]);
      a0 = fmaf(h, bf2f(wd[2 * e - 8]), a0);
      a1 = fmaf(h, bf2f(wd[2 * e - 7]), a1);
    }
#pragma unroll
    for (int off = 32; off; off >>= 1) {
      a0 += __shfl_xor(a0, off, 64);
      a1 += __shfl_xor(a1, off, 64);
    }
    if (lane == 0) {
      out[(size_t)row * 2 + 0] = a0 + b0;
      out[(size_t)row * 2 + 1] = a1 + b1;
    }
  }
}

// ---------------------------------------------------------------- launch
extern "C" void kernel_launch(void* const* d_in, const int* in_sizes, int n_in,
                              void* d_out, int out_size, void* d_ws, size_t ws_size,
                              hipStream_t stream) {
  const float* x     = (const float*)d_in[0];
  const float* e_w1  = (const float*)d_in[1];
  const float* e_b1  = (const float*)d_in[2];
  const float* e_w2  = (const float*)d_in[3];
  const float* e_b2  = (const float*)d_in[4];
  const float* hop_w = (const float*)d_in[5];
  const float* n_w1  = (const float*)d_in[6];
  const float* n_b1  = (const float*)d_in[7];
  const float* n_w2  = (const float*)d_in[8];
  const float* n_b2  = (const float*)d_in[9];
  const float* n_w3  = (const float*)d_in[10];
  const float* n_b3  = (const float*)d_in[11];
  float* out = (float*)d_out;
  char* ws = (char*)d_ws;

  float*    h1e  = (float*)(ws + 0);              // 32768x1024 f32, [0,128MB)
  uint16_t* h1   = (uint16_t*)(ws + 0);           // 32768x1024 bf16 (phase C)
  uint16_t* h2   = (uint16_t*)(ws + 67108864);    // bf16, written AFTER h1e dead
  uint16_t* comb = (uint16_t*)(ws + 134217728);
  float*    enc  = (float*)(ws + 171966464);
  uint16_t* w1t  = (uint16_t*)(ws + 180355072);
  uint16_t* w2t  = (uint16_t*)(ws + 181534720);
  uint16_t* w3b  = (uint16_t*)(ws + 183631872);

  k_conv_x<<<8192, 256, 0, stream>>>(x, comb);
  k_convT<<<dim3(1024 / 64, 576 / 64), 256, 0, stream>>>(n_w1, w1t, 576, 1024);
  k_convT<<<dim3(1024 / 64, 1024 / 64), 256, 0, stream>>>(n_w2, w2t, 1024, 1024);
  k_conv<<<(2048 + 255) / 256, 256, 0, stream>>>(n_w3, w3b, 2048);

  // encoder e1 — f32 OpenBLAS replica, R14 config (measured optimum)
  k_enc<512, true><<<dim3(1024 / 64, 32768 / 128), 256, 0, stream>>>(
      x, e_w1, e_b1, h1e, 1024);
  // encoder e2 — M-split (BM=32, 1024 blocks), full-K chain per element
  k_enc2<<<1024, 256, 0, stream>>>(h1e, e_w2, e_b2, enc);

  // hopfield — bitmask state, runtime loops
  k_hopfield<<<32768 / 32, 256, 0, stream>>>(enc, hop_w, comb);

  // Q-network (bf16 MFMA, gload_lds + XCD swizzle)
  k_gemm_bf16<<<dim3(1024 / 128, 32768 / 128), 256, 0, stream>>>(
      comb, w1t, n_b1, h1, 32768, 1024, 576, 1);
  k_gemm_bf16<<<dim3(1024 / 128, 32768 / 128), 256, 0, stream>>>(
      h1, w2t, n_b2, h2, 32768, 1024, 1024, 1);
  k_n3<<<512, 256, 0, stream>>>(h2, w3b, n_b3, out, 32768);
}

// Round 19
// 969.717 us; speedup vs baseline: 1.0887x; 1.0052x over previous
//
#include <hip/hip_runtime.h>
#include <hip/hip_bf16.h>
#include <stdint.h>
#include <math.h>

typedef __attribute__((ext_vector_type(4))) float f32x4;
typedef __attribute__((ext_vector_type(8))) __bf16 bf16x8;
typedef __attribute__((ext_vector_type(8))) uint16_t u16x8;
typedef __attribute__((ext_vector_type(4))) uint32_t u32x4;

__device__ __forceinline__ uint16_t f2bf(float f) {
  union { float f; uint32_t u; } v; v.f = f;
  uint32_t r = v.u + 0x7FFFu + ((v.u >> 16) & 1u);
  return (uint16_t)(r >> 16);
}
__device__ __forceinline__ float bf2f(uint16_t b) {
  union { uint32_t u; float f; } v; v.u = ((uint32_t)b) << 16;
  return v.f;
}
__device__ __forceinline__ void gload16(const void* g, void* l) {
  __builtin_amdgcn_global_load_lds(
      (const __attribute__((address_space(1))) uint32_t*)g,
      (__attribute__((address_space(3))) uint32_t*)l, 16, 0, 0);
}

// ---------------------------------------------------------------- converts
__global__ __launch_bounds__(256) void k_conv_x(const float* __restrict__ x,
                                                uint16_t* __restrict__ comb) {
  int i = blockIdx.x * 256 + threadIdx.x;
  int base = i * 8;
  int row = base >> 9;
  int col = base & 511;
  const float* src = x + base;
  f32x4 a = *(const f32x4*)src;
  f32x4 b = *(const f32x4*)(src + 4);
  u16x8 o;
  o[0] = f2bf(a[0]); o[1] = f2bf(a[1]); o[2] = f2bf(a[2]); o[3] = f2bf(a[3]);
  o[4] = f2bf(b[0]); o[5] = f2bf(b[1]); o[6] = f2bf(b[2]); o[7] = f2bf(b[3]);
  *(u16x8*)(comb + (size_t)row * 576 + col) = o;
}

// tiled transpose: W[K][N] f32 -> WT[N][K] bf16, both sides coalesced
__global__ __launch_bounds__(256) void k_convT(const float* __restrict__ W,
                                               uint16_t* __restrict__ WT,
                                               int K, int N) {
  __shared__ float tile[64][65];
  const int t = threadIdx.x;
  const int n0 = blockIdx.x * 64, k0 = blockIdx.y * 64;
  const int c = t & 63, r0 = t >> 6;
#pragma unroll
  for (int rr = 0; rr < 16; ++rr) {
    int r = r0 * 16 + rr;
    tile[r][c] = W[(size_t)(k0 + r) * N + n0 + c];
  }
  __syncthreads();
#pragma unroll
  for (int rr = 0; rr < 16; ++rr) {
    int r = r0 * 16 + rr;
    WT[(size_t)(n0 + r) * K + k0 + c] = f2bf(tile[c][r]);
  }
}

__global__ __launch_bounds__(256) void k_conv(const float* __restrict__ W,
                                              uint16_t* __restrict__ O, int n) {
  int i = blockIdx.x * 256 + threadIdx.x;
  if (i < n) O[i] = f2bf(W[i]);
}

// ---------------------------------------------------------------- encoder e1
// f32 OpenBLAS-replica accumulation (bit-exact, PASSING since R10).
// R14 config (the measured optimum: VGPR=64, zero spill, 4 waves/EU).
// R19 single change: ws staging via global_load_lds width-16 (no VGPR
// round-trip). ws unpadded [32][64]: dst byte = w*1024 + lane*16 (lane-
// linear, m104-compliant); reads &ws[k][ng*4] are 2-way-bank = free (m136).
template <int K, bool RELU>
__global__ __launch_bounds__(256, 4)
void k_enc(const float* __restrict__ A, const float* __restrict__ W,
           const float* __restrict__ bias, float* __restrict__ C, int N) {
  __shared__ __align__(16) float xs[32][128];  // [k][m]
  __shared__ __align__(16) float ws[32][64];   // [k][n], unpadded (gload_lds)
  const int t = threadIdx.x;
  const int m0 = blockIdx.y * 128, n0 = blockIdx.x * 64;
  const int mg = t >> 4, ng = t & 15;

  float res[8][4], acc[8][4];
#pragma unroll
  for (int i = 0; i < 8; ++i)
#pragma unroll
    for (int j = 0; j < 4; ++j) { res[i][j] = 0.f; acc[i][j] = 0.f; }

  const int xr = t >> 1, xk = (t & 1) * 16;
  // ws staging: thread t covers ws[t>>4][(t&15)*4] and ws[16+(t>>4)][...]
  const int wr0 = t >> 4, wcol = (t & 15) * 4;
  const float* Wp0 = W + (size_t)wr0 * N + n0 + wcol;          // row wr0
  const float* Wp1 = W + (size_t)(wr0 + 16) * N + n0 + wcol;   // row wr0+16
  float* wl0 = &ws[wr0][wcol];
  float* wl1 = &ws[wr0 + 16][wcol];

  for (int c = 0; c < K / 32; ++c) {
    const int k0 = c * 32;
    if (k0 > 0 && (k0 % 384) == 0) {  // OpenBLAS kc-panel boundary (Q=384)
#pragma unroll
      for (int i = 0; i < 8; ++i)
#pragma unroll
        for (int j = 0; j < 4; ++j) { res[i][j] += acc[i][j]; acc[i][j] = 0.f; }
    }
    __syncthreads();
#pragma unroll
    for (int u = 0; u < 4; ++u) {
      f32x4 v = *(const f32x4*)(A + (size_t)(m0 + xr) * K + k0 + xk + u * 4);
      xs[xk + u * 4 + 0][xr] = v[0];
      xs[xk + u * 4 + 1][xr] = v[1];
      xs[xk + u * 4 + 2][xr] = v[2];
      xs[xk + u * 4 + 3][xr] = v[3];
    }
    gload16(Wp0 + (size_t)k0 * N, wl0);
    gload16(Wp1 + (size_t)k0 * N, wl1);
    __syncthreads();  // drains lgkmcnt (xs) + vmcnt (gload_lds)
#pragma unroll
    for (int k = 0; k < 32; ++k) {
      f32x4 x0 = *(const f32x4*)&xs[k][mg * 8];
      f32x4 x1 = *(const f32x4*)&xs[k][mg * 8 + 4];
      f32x4 wv = *(const f32x4*)&ws[k][ng * 4];
#pragma unroll
      for (int j = 0; j < 4; ++j) {
        acc[0][j] = fmaf(x0[0], wv[j], acc[0][j]);
        acc[1][j] = fmaf(x0[1], wv[j], acc[1][j]);
        acc[2][j] = fmaf(x0[2], wv[j], acc[2][j]);
        acc[3][j] = fmaf(x0[3], wv[j], acc[3][j]);
        acc[4][j] = fmaf(x1[0], wv[j], acc[4][j]);
        acc[5][j] = fmaf(x1[1], wv[j], acc[5][j]);
        acc[6][j] = fmaf(x1[2], wv[j], acc[6][j]);
        acc[7][j] = fmaf(x1[3], wv[j], acc[7][j]);
      }
    }
  }
#pragma unroll
  for (int i = 0; i < 8; ++i)
#pragma unroll
    for (int j = 0; j < 4; ++j) res[i][j] += acc[i][j];  // final panel join

#pragma unroll
  for (int i = 0; i < 8; ++i) {
    f32x4 o;
#pragma unroll
    for (int j = 0; j < 4; ++j) {
      float v = res[i][j] + bias[n0 + ng * 4 + j];
      if (RELU) v = fmaxf(v, 0.f);
      o[j] = v;
    }
    *(f32x4*)(C + (size_t)(m0 + mg * 8 + i) * N + n0 + ng * 4) = o;
  }
}

// ---------------------------------------------------------------- encoder e2
// M-split (BM=32, 1024 blocks), full-K chain per element (R16, passing).
__global__ __launch_bounds__(256, 8)
void k_enc2(const float* __restrict__ A, const float* __restrict__ W,
            const float* __restrict__ bias, float* __restrict__ C) {
  __shared__ __align__(16) float xs[32][36];  // [k][m], +4 pad
  __shared__ __align__(16) float ws[32][68];  // [k][n], +4 pad
  const int t = threadIdx.x;
  const int m0 = blockIdx.x * 32;
  const int mg = t >> 4, ng = t & 15;  // rows mg*2..+1, cols ng*4..+3

  float res[2][4] = {}, acc[2][4] = {};
  const int xr = t >> 3, xk4 = (t & 7) * 4;
  const int wrr = t >> 3, wj = (t & 7) * 8;

  for (int c = 0; c < 32; ++c) {  // K = 1024
    const int k0 = c * 32;
    if (k0 > 0 && (k0 % 384) == 0) {  // kc-panel joins (384, 768)
#pragma unroll
      for (int i = 0; i < 2; ++i)
#pragma unroll
        for (int j = 0; j < 4; ++j) { res[i][j] += acc[i][j]; acc[i][j] = 0.f; }
    }
    __syncthreads();
    {
      f32x4 v = *(const f32x4*)(A + (size_t)(m0 + xr) * 1024 + k0 + xk4);
      xs[xk4 + 0][xr] = v[0];
      xs[xk4 + 1][xr] = v[1];
      xs[xk4 + 2][xr] = v[2];
      xs[xk4 + 3][xr] = v[3];
    }
#pragma unroll
    for (int u = 0; u < 2; ++u)
      *(f32x4*)&ws[wrr][wj + u * 4] =
          *(const f32x4*)(W + (size_t)(k0 + wrr) * 64 + wj + u * 4);
    __syncthreads();
#pragma unroll
    for (int k = 0; k < 32; ++k) {
      float x0 = xs[k][mg * 2 + 0];
      float x1 = xs[k][mg * 2 + 1];
      f32x4 wv = *(const f32x4*)&ws[k][ng * 4];
#pragma unroll
      for (int j = 0; j < 4; ++j) {
        acc[0][j] = fmaf(x0, wv[j], acc[0][j]);
        acc[1][j] = fmaf(x1, wv[j], acc[1][j]);
      }
    }
  }
#pragma unroll
  for (int i = 0; i < 2; ++i)
#pragma unroll
    for (int j = 0; j < 4; ++j) res[i][j] += acc[i][j];  // final panel join

#pragma unroll
  for (int i = 0; i < 2; ++i) {
    f32x4 o;
#pragma unroll
    for (int j = 0; j < 4; ++j) o[j] = res[i][j] + bias[ng * 4 + j];
    *(f32x4*)(C + (size_t)(m0 + mg * 2 + i) * 64 + ng * 4) = o;
  }
}

// ---------------------------------------------------------------- Hopfield
// PASSING arithmetic (R10): f32 state, numpy pairwise-8 tree, tie -> -1.
// Bitmask state + runtime loops (R14, no spill).
#define KNIFE_TAU 1e-6f

__device__ __forceinline__ uint32_t retrieve_bits(uint32_t sm,
                                                  const float (*w)[64],
                                                  int l) {
  for (int it = 0; it < 10; ++it) {
    bool changed = false;
    for (int i = 0; i < 64; ++i) {
      float r = 0.f;
#pragma unroll
      for (int c = 0; c < 8; ++c) {
        float wv = w[i][8 * c + l];
        uint32_t flip = ((~sm >> c) & 1u) << 31;  // bit clear -> s=-1 -> -wv
        r += __uint_as_float(__float_as_uint(wv) ^ flip);
      }
      r += __shfl_xor(r, 1);
      r += __shfl_xor(r, 2);
      r += __shfl_xor(r, 4);
      uint32_t nb = r > 0.f ? 1u : 0u;  // np: where(act > 0, 1, -1)
      if ((i & 7) == l) {
        uint32_t g = i >> 3;
        uint32_t ob = (sm >> g) & 1u;
        changed |= (nb != ob);
        sm = (sm & ~(1u << g)) | (nb << g);
      }
    }
    if (!__any(changed)) break;
  }
  return sm;
}

__device__ __forceinline__ uint64_t gather_mask_bits(uint32_t sm, int g) {
  uint64_t m = 0;
#pragma unroll
  for (int c = 0; c < 8; ++c) {
    unsigned long long b = __ballot(((sm >> c) & 1u) != 0u);
    m |= (uint64_t)((b >> (g * 8)) & 0xFFull) << (8 * c);
  }
  return m;
}

__global__ __launch_bounds__(256) void k_hopfield(const float* __restrict__ enc,
                                                  const float* __restrict__ hw,
                                                  uint16_t* __restrict__ comb) {
  __shared__ __align__(16) float w[64][64];
  const int t = threadIdx.x;
#pragma unroll
  for (int i = 0; i < 4; ++i)
    ((f32x4*)&w[0][0])[t * 4 + i] = ((const f32x4*)hw)[t * 4 + i];
  __syncthreads();

  const int lane = t & 63, wv = t >> 6;
  const int g = lane >> 3, l = lane & 7;
  const int sid = (blockIdx.x * 4 + wv) * 8 + g;
  const float* er = enc + (size_t)sid * 64;

  uint32_t imask = 0;
  int kc = -1;
  bool kpos = false;
#pragma unroll
  for (int c = 0; c < 8; ++c) {
    float v = er[8 * c + l];
    if (v > 0.f) imask |= (1u << c);
    if (kc < 0 && fabsf(v) < KNIFE_TAU) { kc = c; kpos = v > 0.f; }
  }
  unsigned long long kb = __ballot(kc >= 0);
  uint32_t gbits = (uint32_t)((kb >> (g * 8)) & 0xFFull);
  bool hasknife = gbits != 0;
  int klane = g * 8 + (__ffs(gbits) - 1);
  bool is_kl = hasknife && (lane == klane);
  uint32_t kbit = (kc >= 0) ? (1u << (kc & 7)) : 0u;

  uint32_t ma_bits = is_kl ? (imask | kbit) : imask;
  uint64_t mA = gather_mask_bits(retrieve_bits(ma_bits, w, l), g);
  uint64_t m = mA;

  if (__any(hasknife)) {
    if (hasknife) {
      uint32_t mb_bits = is_kl ? (imask & ~kbit) : imask;
      uint64_t mB = gather_mask_bits(retrieve_bits(mb_bits, w, l), g);
      if (mA != mB) {
        int kp = __shfl(kpos ? 1 : 0, klane);
        m = kp ? mA : mB;
      }
    }
  }

  uint32_t byte = (uint32_t)((m >> (8 * l)) & 0xFFull);
  u32x4 o;
#pragma unroll
  for (int p = 0; p < 4; ++p) {
    uint32_t lo = ((byte >> (2 * p)) & 1u) ? 0x3F80u : 0u;
    uint32_t hi = ((byte >> (2 * p + 1)) & 1u) ? 0x3F800000u : 0u;
    o[p] = lo | hi;
  }
  *(u32x4*)(comb + (size_t)sid * 576 + 512 + l * 8) = o;
}

// ---------------------------------------------------------------- bf16 MFMA GEMM
// global_load_lds staging (R12) + bijective T1 XCD swizzle (R15).
__global__ __launch_bounds__(256)
void k_gemm_bf16(const uint16_t* __restrict__ A, const uint16_t* __restrict__ BT,
                 const float* __restrict__ bias, uint16_t* __restrict__ C,
                 int M, int N, int K, int relu) {
  constexpr int BM = 128, BN = 128, BK = 32;
  __shared__ __align__(16) uint16_t As[BM][BK];
  __shared__ __align__(16) uint16_t Bs[BN][BK];
  const int t = threadIdx.x;
  const int lane = t & 63, wid = t >> 6;
  const int wr = wid >> 1, wc = wid & 1;

  int bxi = blockIdx.x, byi = blockIdx.y;
  if ((gridDim.x & 7) == 0) {
    int L = byi * gridDim.x + bxi;
    int cpx = (gridDim.x * gridDim.y) >> 3;
    int T = (L & 7) * cpx + (L >> 3);
    byi = T / gridDim.x;
    bxi = T % gridDim.x;
  }
  const int bm = byi * BM, bn = bxi * BN;

  f32x4 acc[4][4] = {};

  const int l15 = lane & 15, kb = (lane >> 4) * 8;
  const int i0 = t, i1 = t + 256;
  const int r0 = i0 >> 2, c0 = (i0 & 3) * 8;
  const int r1 = i1 >> 2, c1 = (i1 & 3) * 8;
  const uint16_t* A0 = A + (size_t)(bm + r0) * K + c0;
  const uint16_t* A1 = A + (size_t)(bm + r1) * K + c1;
  const uint16_t* B0 = BT + (size_t)(bn + r0) * K + c0;
  const uint16_t* B1 = BT + (size_t)(bn + r1) * K + c1;
  uint16_t* Al = &As[0][0];
  uint16_t* Bl = &Bs[0][0];

  for (int kt = 0; kt < K / BK; ++kt) {
    __syncthreads();
    const int ko = kt * BK;
    gload16(A0 + ko, Al + i0 * 8);
    gload16(A1 + ko, Al + i1 * 8);
    gload16(B0 + ko, Bl + i0 * 8);
    gload16(B1 + ko, Bl + i1 * 8);
    __syncthreads();
    bf16x8 af[4], bf[4];
#pragma unroll
    for (int m = 0; m < 4; ++m)
      af[m] = *(const bf16x8*)&As[wr * 64 + m * 16 + l15][kb];
#pragma unroll
    for (int n = 0; n < 4; ++n)
      bf[n] = *(const bf16x8*)&Bs[wc * 64 + n * 16 + l15][kb];
#pragma unroll
    for (int m = 0; m < 4; ++m)
#pragma unroll
      for (int n = 0; n < 4; ++n)
        acc[m][n] = __builtin_amdgcn_mfma_f32_16x16x32_bf16(af[m], bf[n],
                                                            acc[m][n], 0, 0, 0);
  }
#pragma unroll
  for (int m = 0; m < 4; ++m) {
    int row = bm + wr * 64 + m * 16 + (lane >> 4) * 4;
#pragma unroll
    for (int n = 0; n < 4; ++n) {
      int col = bn + wc * 64 + n * 16 + l15;
      float bsv = bias[col];
#pragma unroll
      for (int r = 0; r < 4; ++r) {
        float v = acc[m][n][r] + bsv;
        if (relu) v = fmaxf(v, 0.f);
        C[(size_t)(row + r) * N + col] = f2bf(v);
      }
    }
  }
}

// ---------------------------------------------------------------- n3 (N=2)
__global__ __launch_bounds__(256) void k_n3(const uint16_t* __restrict__ h2,
                                            const uint16_t* __restrict__ w3,
                                            const float* __restrict__ b3,
                                            float* __restrict__ out, int M) {
  const int lane = threadIdx.x & 63;
  const int wglob = (blockIdx.x * 256 + threadIdx.x) >> 6;
  const int nw = (gridDim.x * 256) >> 6;
  u16x8 wa = *(const u16x8*)(w3 + lane * 16);
  u16x8 wb = *(const u16x8*)(w3 + lane * 16 + 8);
  u16x8 wc = *(const u16x8*)(w3 + 1024 + lane * 16);
  u16x8 wd = *(const u16x8*)(w3 + 1024 + lane * 16 + 8);
  const float b0 = b3[0], b1 = b3[1];
  for (int row = wglob; row < M; row += nw) {
    const uint16_t* hr = h2 + (size_t)row * 1024;
    u16x8 h0 = *(const u16x8*)(hr + lane * 8);
    u16x8 h1 = *(const u16x8*)(hr + 512 + lane * 8);
    float a0 = 0.f, a1 = 0.f;
#pragma unroll
    for (int e = 0; e < 4; ++e) {
      float h = bf2f(h0[e]);
      a0 = fmaf(h, bf2f(wa[2 * e]), a0);
      a1 = fmaf(h, bf2f(wa[2 * e + 1]), a1);
    }
#pragma unroll
    for (int e = 4; e < 8; ++e) {
      float h = bf2f(h0[e]);
      a0 = fmaf(h, bf2f(wb[2 * e - 8]), a0);
      a1 = fmaf(h, bf2f(wb[2 * e - 7]), a1);
    }
#pragma unroll
    for (int e = 0; e < 4; ++e) {
      float h = bf2f(h1[e]);
      a0 = fmaf(h, bf2f(wc[2 * e]), a0);
      a1 = fmaf(h, bf2f(wc[2 * e + 1]), a1);
    }
#pragma unroll
    for (int e = 4; e < 8; ++e) {
      float h = bf2f(h1[e]);
      a0 = fmaf(h, bf2f(wd[2 * e - 8]), a0);
      a1 = fmaf(h, bf2f(wd[2 * e - 7]), a1);
    }
#pragma unroll
    for (int off = 32; off; off >>= 1) {
      a0 += __shfl_xor(a0, off, 64);
      a1 += __shfl_xor(a1, off, 64);
    }
    if (lane == 0) {
      out[(size_t)row * 2 + 0] = a0 + b0;
      out[(size_t)row * 2 + 1] = a1 + b1;
    }
  }
}

// ---------------------------------------------------------------- launch
extern "C" void kernel_launch(void* const* d_in, const int* in_sizes, int n_in,
                              void* d_out, int out_size, void* d_ws, size_t ws_size,
                              hipStream_t stream) {
  const float* x     = (const float*)d_in[0];
  const float* e_w1  = (const float*)d_in[1];
  const float* e_b1  = (const float*)d_in[2];
  const float* e_w2  = (const float*)d_in[3];
  const float* e_b2  = (const float*)d_in[4];
  const float* hop_w = (const float*)d_in[5];
  const float* n_w1  = (const float*)d_in[6];
  const float* n_b1  = (const float*)d_in[7];
  const float* n_w2  = (const float*)d_in[8];
  const float* n_b2  = (const float*)d_in[9];
  const float* n_w3  = (const float*)d_in[10];
  const float* n_b3  = (const float*)d_in[11];
  float* out = (float*)d_out;
  char* ws = (char*)d_ws;

  float*    h1e  = (float*)(ws + 0);              // 32768x1024 f32, [0,128MB)
  uint16_t* h1   = (uint16_t*)(ws + 0);           // 32768x1024 bf16 (phase C)
  uint16_t* h2   = (uint16_t*)(ws + 67108864);    // bf16, written AFTER h1e dead
  uint16_t* comb = (uint16_t*)(ws + 134217728);
  float*    enc  = (float*)(ws + 171966464);
  uint16_t* w1t  = (uint16_t*)(ws + 180355072);
  uint16_t* w2t  = (uint16_t*)(ws + 181534720);
  uint16_t* w3b  = (uint16_t*)(ws + 183631872);

  k_conv_x<<<8192, 256, 0, stream>>>(x, comb);
  k_convT<<<dim3(1024 / 64, 576 / 64), 256, 0, stream>>>(n_w1, w1t, 576, 1024);
  k_convT<<<dim3(1024 / 64, 1024 / 64), 256, 0, stream>>>(n_w2, w2t, 1024, 1024);
  k_conv<<<(2048 + 255) / 256, 256, 0, stream>>>(n_w3, w3b, 2048);

  // encoder e1 — f32 OpenBLAS replica, R14 config + gload_lds W-staging
  k_enc<512, true><<<dim3(1024 / 64, 32768 / 128), 256, 0, stream>>>(
      x, e_w1, e_b1, h1e, 1024);
  // encoder e2 — M-split (BM=32, 1024 blocks), full-K chain per element
  k_enc2<<<1024, 256, 0, stream>>>(h1e, e_w2, e_b2, enc);

  // hopfield — bitmask state, runtime loops
  k_hopfield<<<32768 / 32, 256, 0, stream>>>(enc, hop_w, comb);

  // Q-network (bf16 MFMA, gload_lds + XCD swizzle)
  k_gemm_bf16<<<dim3(1024 / 128, 32768 / 128), 256, 0, stream>>>(
      comb, w1t, n_b1, h1, 32768, 1024, 576, 1);
  k_gemm_bf16<<<dim3(1024 / 128, 32768 / 128), 256, 0, stream>>>(
      h1, w2t, n_b2, h2, 32768, 1024, 1024, 1);
  k_n3<<<512, 256, 0, stream>>>(h2, w3b, n_b3, out, 32768);
}